// Round 5
// baseline (115.258 us; speedup 1.0000x reference)
//
#include <hip/hip_runtime.h>
#include <math.h>

// Problem constants (fixed by reference setup_inputs)
#define N_TOT 8192
#define M_TOT 16384
#define EPS_N 1024
#define N_EMB 16

#define LOG2E 1.4426950408889634f
#define LN2   0.6931471805599453f
#define EXP2(x)   __builtin_amdgcn_exp2f(x)   // v_exp_f32
#define LOG2F_(x) __builtin_amdgcn_logf(x)    // v_log_f32 (log2)

// K1: product-grid factorization e_j = m_k + T*u_l  (j = k*1024 + l)
//   t_ij = A_ik + B_il,  P=2^A, Q=2^B, S_kl = sum_i P_ik Q_il
// R5: k split across grid.z (8 k's per block) so acc[8][4]=32 regs — R4's
// acc[16][4]=64 + pk[16] spilled at VGPR_Count=52 (49.6 us, VALUBusy 4.9%).
#define BLK1  512
#define IC    128                 // i's per block (8 waves x 16)
#define NICH  (N_TOT / IC)        // 64
#define LCH   256                 // l's per block
#define NLCH  (EPS_N / LCH)       // 4
#define NQ    (LCH / 64)          // 4 l's per lane
#define KC    8                   // k's per block
#define NKCH  (N_EMB / KC)        // 2

__global__ __launch_bounds__(BLK1, 4) void gemm_partial_kernel(
    const float* __restrict__ z, const float* __restrict__ emb,
    const float* __restrict__ log_sigma, const float* __restrict__ eps,
    const float* __restrict__ temperature, float* __restrict__ part,
    unsigned int* __restrict__ counter)
{
    __shared__ __align__(16) float4 prow[IC * 2];     // 4 KB: P_ik, 2 quads per i
    __shared__ __align__(16) float2 tbrow[IC];        // 1 KB: (T*b0, T*b1) per i
    __shared__ __align__(16) float  tile[KC * LCH];   // 8 KB ds_add accumulation tile

    const int t  = threadIdx.x;
    const int l0 = blockIdx.x * LCH;
    const int ib = blockIdx.y;
    const int kb = blockIdx.z;                        // k-chunk: k = kb*8 + 0..7

    // zero K2's finalize counter (visible to K2 across the dispatch boundary)
    if (blockIdx.x == 0 && ib == 0 && kb == 0 && t == 0) *counter = 0u;

    const float ls = log_sigma[0];
    const float T  = temperature[0];
    const float alpha = -0.5f * EXP2(LOG2E * (-2.0f * ls));  // -1/(2 sigma^2)
    const float La  = LOG2E * alpha;
    const float omT = 1.0f - T;

    // Phase A: 512 threads = 128 i's x 4 roles. Roles 0/1: P-quads, 2: tb, 3: idle.
    {
        const int il   = t & (IC - 1);
        const int role = t >> 7;
        const int i  = ib * IC + il;
        const float z0 = z[2 * i], z1 = z[2 * i + 1];
        const float c  = La * (z0 * z0 + z1 * z1);
        const float b0 = -2.0f * La * z0, b1 = -2.0f * La * z1;
        if (role < 2) {
            float4 p;
#pragma unroll
            for (int kk = 0; kk < 4; ++kk) {
                const int k = kb * KC + role * 4 + kk;
                const float m0 = omT * emb[2 * k], m1 = omT * emb[2 * k + 1];
                ((float*)&p)[kk] = EXP2(c + b0 * m0 + b1 * m1);   // P_ik
            }
            prow[il * 2 + role] = p;
        } else if (role == 2) {
            tbrow[il] = make_float2(T * b0, T * b1);
        }
        ((float4*)tile)[t] = make_float4(0.0f, 0.0f, 0.0f, 0.0f); // zero 8 KB tile
    }

    const int lane = t & 63;
    const int w    = t >> 6;                    // 8 waves, 16 i each
    const float2* eps2 = (const float2*)eps;
    float2 u[NQ];
#pragma unroll
    for (int q = 0; q < NQ; ++q) u[q] = eps2[l0 + lane + 64 * q];

    __syncthreads();

    float acc[KC][NQ];
#pragma unroll
    for (int k = 0; k < KC; ++k)
#pragma unroll
        for (int q = 0; q < NQ; ++q) acc[k][q] = 0.0f;

    const int ibase = w * (IC / 8);
    for (int n = 0; n < IC / 8; ++n) {
        const int ir = ibase + n;
        const float4 p0 = prow[ir * 2];         // wave-uniform broadcast reads
        const float4 p1 = prow[ir * 2 + 1];
        const float2 tb = tbrow[ir];
        float qv[NQ];
#pragma unroll
        for (int q = 0; q < NQ; ++q)
            qv[q] = EXP2(fmaf(tb.y, u[q].y, tb.x * u[q].x));   // Q_il
        float pk[KC];
        *(float4*)&pk[0] = p0; *(float4*)&pk[4] = p1;
#pragma unroll
        for (int k = 0; k < KC; ++k)
#pragma unroll
            for (int q = 0; q < NQ; ++q)
                acc[k][q] = fmaf(pk[k], qv[q], acc[k][q]);
    }

    // Phase C: cross-wave combine via LDS float atomics (lane-contiguous: 2/bank, free)
#pragma unroll
    for (int k = 0; k < KC; ++k)
#pragma unroll
        for (int q = 0; q < NQ; ++q)
            atomicAdd(&tile[k * LCH + lane + 64 * q], acc[k][q]);
    __syncthreads();

    // write this block's 8 x 256 partial to global (coalesced float4 stores)
    {
        const int e  = t * 4;                   // 2048 floats / 512 threads
        const int kt = e >> 8;                  // / LCH
        const int lo = e & (LCH - 1);
        float* dst = part + (size_t)ib * M_TOT + (kb * KC + kt) * EPS_N + l0 + lo;
        *(float4*)dst = ((float4*)tile)[t];
    }
}

// K2: combine partials, v_j = g_j + log2(S_j); block scalar; last block finalizes loss
#define BLK2 256
__global__ __launch_bounds__(BLK2) void reduce_final_kernel(
    const float* __restrict__ emb, const float* __restrict__ log_sigma,
    const float* __restrict__ eps, const float* __restrict__ temperature,
    const float* __restrict__ part, float* __restrict__ sc,
    unsigned int* __restrict__ counter, float* __restrict__ out)
{
    const int t = threadIdx.x;
    const int j = blockIdx.x * BLK2 + t;
    const float ls = log_sigma[0];
    const float T  = temperature[0];
    const float alpha = -0.5f * EXP2(LOG2E * (-2.0f * ls));

    float S = 0.0f;
#pragma unroll 8
    for (int ib = 0; ib < NICH; ++ib)
        S += part[(size_t)ib * M_TOT + j];      // coalesced across threads

    const int k = j >> 10, l = j & (EPS_N - 1);
    const float omT = 1.0f - T;
    const float e0 = omT * emb[2 * k]     + T * eps[2 * l];
    const float e1 = omT * emb[2 * k + 1] + T * eps[2 * l + 1];
    const float g  = LOG2E * alpha * (e0 * e0 + e1 * e1);   // factored-out 2^g

    float v = g + LOG2F_(S);                    // lse_j / ln2

#pragma unroll
    for (int off = 32; off; off >>= 1) v += __shfl_down(v, off, 64);
    __shared__ float wsum[BLK2 / 64];
    const int lane = t & 63, w = t >> 6;
    if (lane == 0) wsum[w] = v;
    __syncthreads();

    __shared__ int is_last;
    if (t == 0) {
        sc[blockIdx.x] = wsum[0] + wsum[1] + wsum[2] + wsum[3];
        __threadfence();                        // release block scalar
        unsigned int old = atomicAdd(counter, 1u);
        is_last = (old == (unsigned)(M_TOT / BLK2 - 1));
    }
    __syncthreads();

    if (is_last && t < 64) {
        __threadfence();                        // acquire other blocks' scalars
        float x = sc[t];                        // exactly 64 block scalars
#pragma unroll
        for (int off = 32; off; off >>= 1) x += __shfl_down(x, off, 64);
        if (t == 0) {
            const float sum_lse = x * LN2;
            // loss = -mean(lse) + 0.5*z_dim*(2*ls - 1) + log(n);  z_dim=2, n=8192
            out[0] = -sum_lse / (float)M_TOT + (2.0f * ls - 1.0f) + 9.010913347279288f;
        }
    }
}

extern "C" void kernel_launch(void* const* d_in, const int* in_sizes, int n_in,
                              void* d_out, int out_size, void* d_ws, size_t ws_size,
                              hipStream_t stream)
{
    const float* z    = (const float*)d_in[0];
    const float* emb  = (const float*)d_in[1];
    const float* lsig = (const float*)d_in[2];
    const float* eps  = (const float*)d_in[3];
    const float* temp = (const float*)d_in[4];

    float*        part    = (float*)d_ws;                    // 64 x 16384 floats = 4 MB
    float*        sc      = part + (size_t)NICH * M_TOT;     // 64 floats
    unsigned int* counter = (unsigned int*)(sc + 64);        // 1 uint (zeroed by K1)

    dim3 grid1(NLCH, NICH, NKCH);                            // 4 x 64 x 2 = 512 blocks
    gemm_partial_kernel<<<grid1, BLK1, 0, stream>>>(z, emb, lsig, eps, temp, part, counter);
    reduce_final_kernel<<<M_TOT / BLK2, BLK2, 0, stream>>>(emb, lsig, eps, temp, part, sc,
                                                           counter, (float*)d_out);
}

// Round 6
// 113.778 us; speedup vs baseline: 1.0130x; 1.0130x over previous
//
#include <hip/hip_runtime.h>
#include <math.h>

// Problem constants (fixed by reference setup_inputs)
#define N_TOT 8192
#define M_TOT 16384
#define EPS_N 1024
#define N_EMB 16

#define LOG2E 1.4426950408889634f
#define LN2   0.6931471805599453f
#define EXP2(x)   __builtin_amdgcn_exp2f(x)   // v_exp_f32
#define LOG2F_(x) __builtin_amdgcn_logf(x)    // v_log_f32 (log2)

// K1: product-grid factorization e_j = m_k + T*u_l  (j = k*1024 + l)
//   t_ij = A_ik + B_il,  P=2^A, Q=2^B, S_kl = sum_i P_ik Q_il
// R6: NO address-taken private arrays. R4/R5's `*(float4*)&pk[0]` punning put
// pk/acc on the STACK (FETCH_SIZE 200 MB of scratch traffic, VGPR_Count 36,
// VALUBusy 9% — latency-bound on scratch, 50 us). Everything below is named
// scalars + direct .x/.y/.z/.w access so SROA keeps it in VGPRs.
#define BLK1  512
#define IC    128                 // i's per block (8 waves x 16)
#define NICH  (N_TOT / IC)        // 64
#define LCH   256                 // l's per block
#define NLCH  (EPS_N / LCH)       // 4
#define KC    8                   // k's per block
#define NKCH  (N_EMB / KC)        // 2

__global__ __launch_bounds__(BLK1) void gemm_partial_kernel(
    const float* __restrict__ z, const float* __restrict__ emb,
    const float* __restrict__ log_sigma, const float* __restrict__ eps,
    const float* __restrict__ temperature, float* __restrict__ part,
    unsigned int* __restrict__ counter)
{
    __shared__ __align__(16) float4 prow[IC * 2];     // 4 KB: P_ik, 2 quads per i
    __shared__ __align__(16) float2 tbrow[IC];        // 1 KB: (T*b0, T*b1) per i
    __shared__ __align__(16) float  tile[KC * LCH];   // 8 KB accumulation tile

    const int t  = threadIdx.x;
    const int l0 = blockIdx.x * LCH;
    const int ib = blockIdx.y;
    const int kb = blockIdx.z;                        // k-chunk: k = kb*8 + 0..7

    // zero K2's finalize counter (visible to K2 across the dispatch boundary)
    if (blockIdx.x == 0 && ib == 0 && kb == 0 && t == 0) *counter = 0u;

    const float ls = log_sigma[0];
    const float T  = temperature[0];
    const float alpha = -0.5f * EXP2(LOG2E * (-2.0f * ls));  // -1/(2 sigma^2)
    const float La  = LOG2E * alpha;
    const float omT = 1.0f - T;

    // Phase A: 512 threads = 128 i's x 4 roles. Roles 0/1: P-quads, 2: tb, 3: idle.
    {
        const int il   = t & (IC - 1);
        const int role = t >> 7;                      // wave-uniform
        const int i  = ib * IC + il;
        const float z0 = z[2 * i], z1 = z[2 * i + 1];
        const float c  = La * (z0 * z0 + z1 * z1);
        const float b0 = -2.0f * La * z0, b1 = -2.0f * La * z1;
        if (role < 2) {
            const int kbase = kb * KC + role * 4;
#define PCOMP(kk) EXP2(c + b0 * (omT * emb[2 * (kbase + (kk))]) \
                         + b1 * (omT * emb[2 * (kbase + (kk)) + 1]))
            const float4 p = make_float4(PCOMP(0), PCOMP(1), PCOMP(2), PCOMP(3));
#undef PCOMP
            prow[il * 2 + role] = p;
        } else if (role == 2) {
            tbrow[il] = make_float2(T * b0, T * b1);
        }
        ((float4*)tile)[t] = make_float4(0.0f, 0.0f, 0.0f, 0.0f); // zero 8 KB tile (LDS)
    }

    const int lane = t & 63;
    const int w    = t >> 6;                    // 8 waves, 16 i each
    const float2* eps2 = (const float2*)eps;
    const float2 u0 = eps2[l0 + lane];
    const float2 u1 = eps2[l0 + 64 + lane];
    const float2 u2 = eps2[l0 + 128 + lane];
    const float2 u3 = eps2[l0 + 192 + lane];

    __syncthreads();

    // 32 named accumulators: a<k><q>, k=0..7, q=0..3
    float a00=0,a01=0,a02=0,a03=0, a10=0,a11=0,a12=0,a13=0;
    float a20=0,a21=0,a22=0,a23=0, a30=0,a31=0,a32=0,a33=0;
    float a40=0,a41=0,a42=0,a43=0, a50=0,a51=0,a52=0,a53=0;
    float a60=0,a61=0,a62=0,a63=0, a70=0,a71=0,a72=0,a73=0;

    const int ibase = w * (IC / 8);
    for (int n = 0; n < IC / 8; ++n) {
        const int ir = ibase + n;
        const float4 p0 = prow[ir * 2];         // wave-uniform broadcast reads
        const float4 p1 = prow[ir * 2 + 1];
        const float2 tb = tbrow[ir];
        const float qv0 = EXP2(fmaf(tb.y, u0.y, tb.x * u0.x));   // Q_il
        const float qv1 = EXP2(fmaf(tb.y, u1.y, tb.x * u1.x));
        const float qv2 = EXP2(fmaf(tb.y, u2.y, tb.x * u2.x));
        const float qv3 = EXP2(fmaf(tb.y, u3.y, tb.x * u3.x));
#define ROW(A0,A1,A2,A3,PC) \
        A0 = fmaf(PC, qv0, A0); A1 = fmaf(PC, qv1, A1); \
        A2 = fmaf(PC, qv2, A2); A3 = fmaf(PC, qv3, A3);
        ROW(a00,a01,a02,a03, p0.x)
        ROW(a10,a11,a12,a13, p0.y)
        ROW(a20,a21,a22,a23, p0.z)
        ROW(a30,a31,a32,a33, p0.w)
        ROW(a40,a41,a42,a43, p1.x)
        ROW(a50,a51,a52,a53, p1.y)
        ROW(a60,a61,a62,a63, p1.z)
        ROW(a70,a71,a72,a73, p1.w)
#undef ROW
    }

    // Phase C: cross-wave combine via LDS float atomics (lane-contiguous: 2/bank, free)
#define PUT(K,A0,A1,A2,A3) \
    atomicAdd(&tile[(K) * LCH + lane],       A0); \
    atomicAdd(&tile[(K) * LCH + 64  + lane], A1); \
    atomicAdd(&tile[(K) * LCH + 128 + lane], A2); \
    atomicAdd(&tile[(K) * LCH + 192 + lane], A3);
    PUT(0,a00,a01,a02,a03) PUT(1,a10,a11,a12,a13)
    PUT(2,a20,a21,a22,a23) PUT(3,a30,a31,a32,a33)
    PUT(4,a40,a41,a42,a43) PUT(5,a50,a51,a52,a53)
    PUT(6,a60,a61,a62,a63) PUT(7,a70,a71,a72,a73)
#undef PUT
    __syncthreads();

    // write this block's 8 x 256 partial to global (coalesced float4 stores)
    {
        const int e  = t * 4;                   // 2048 floats / 512 threads
        const int kt = e >> 8;                  // / LCH
        const int lo = e & (LCH - 1);
        float* dst = part + (size_t)ib * M_TOT + (kb * KC + kt) * EPS_N + l0 + lo;
        *(float4*)dst = ((float4*)tile)[t];     // LDS->global, no private involved
    }
}

// K2: combine partials, v_j = g_j + log2(S_j); block scalar; last block finalizes loss
#define BLK2 256
__global__ __launch_bounds__(BLK2) void reduce_final_kernel(
    const float* __restrict__ emb, const float* __restrict__ log_sigma,
    const float* __restrict__ eps, const float* __restrict__ temperature,
    const float* __restrict__ part, float* __restrict__ sc,
    unsigned int* __restrict__ counter, float* __restrict__ out)
{
    const int t = threadIdx.x;
    const int j = blockIdx.x * BLK2 + t;
    const float ls = log_sigma[0];
    const float T  = temperature[0];
    const float alpha = -0.5f * EXP2(LOG2E * (-2.0f * ls));

    float S = 0.0f;
#pragma unroll 8
    for (int ib = 0; ib < NICH; ++ib)
        S += part[(size_t)ib * M_TOT + j];      // coalesced across threads

    const int k = j >> 10, l = j & (EPS_N - 1);
    const float omT = 1.0f - T;
    const float e0 = omT * emb[2 * k]     + T * eps[2 * l];
    const float e1 = omT * emb[2 * k + 1] + T * eps[2 * l + 1];
    const float g  = LOG2E * alpha * (e0 * e0 + e1 * e1);   // factored-out 2^g

    float v = g + LOG2F_(S);                    // lse_j / ln2

#pragma unroll
    for (int off = 32; off; off >>= 1) v += __shfl_down(v, off, 64);
    __shared__ float wsum[BLK2 / 64];
    const int lane = t & 63, w = t >> 6;
    if (lane == 0) wsum[w] = v;
    __syncthreads();

    __shared__ int is_last;
    if (t == 0) {
        sc[blockIdx.x] = wsum[0] + wsum[1] + wsum[2] + wsum[3];
        __threadfence();                        // release block scalar
        unsigned int old = atomicAdd(counter, 1u);
        is_last = (old == (unsigned)(M_TOT / BLK2 - 1));
    }
    __syncthreads();

    if (is_last && t < 64) {
        __threadfence();                        // acquire other blocks' scalars
        float x = sc[t];                        // exactly 64 block scalars
#pragma unroll
        for (int off = 32; off; off >>= 1) x += __shfl_down(x, off, 64);
        if (t == 0) {
            const float sum_lse = x * LN2;
            // loss = -mean(lse) + 0.5*z_dim*(2*ls - 1) + log(n);  z_dim=2, n=8192
            out[0] = -sum_lse / (float)M_TOT + (2.0f * ls - 1.0f) + 9.010913347279288f;
        }
    }
}

extern "C" void kernel_launch(void* const* d_in, const int* in_sizes, int n_in,
                              void* d_out, int out_size, void* d_ws, size_t ws_size,
                              hipStream_t stream)
{
    const float* z    = (const float*)d_in[0];
    const float* emb  = (const float*)d_in[1];
    const float* lsig = (const float*)d_in[2];
    const float* eps  = (const float*)d_in[3];
    const float* temp = (const float*)d_in[4];

    float*        part    = (float*)d_ws;                    // 64 x 16384 floats = 4 MB
    float*        sc      = part + (size_t)NICH * M_TOT;     // 64 floats
    unsigned int* counter = (unsigned int*)(sc + 64);        // 1 uint (zeroed by K1)

    dim3 grid1(NLCH, NICH, NKCH);                            // 4 x 64 x 2 = 512 blocks
    gemm_partial_kernel<<<grid1, BLK1, 0, stream>>>(z, emb, lsig, eps, temp, part, counter);
    reduce_final_kernel<<<M_TOT / BLK2, BLK2, 0, stream>>>(emb, lsig, eps, temp, part, sc,
                                                           counter, (float*)d_out);
}

// Round 7
// 81.578 us; speedup vs baseline: 1.4129x; 1.3947x over previous
//
#include <hip/hip_runtime.h>
#include <math.h>

// Problem constants (fixed by reference setup_inputs)
#define N_TOT 8192
#define M_TOT 16384
#define EPS_N 1024
#define N_EMB 16

#define LOG2E 1.4426950408889634f
#define LN2   0.6931471805599453f
#define EXP2(x)   __builtin_amdgcn_exp2f(x)   // v_exp_f32
#define LOG2F_(x) __builtin_amdgcn_logf(x)    // v_log_f32 (log2)

// K1: product-grid factorization e_j = m_k + T*u_l  (j = k*1024 + l)
//   t_ij = A_ik + B_il,  P=2^A, Q=2^B, S_kl = sum_i P_ik Q_il
//
// R7: back to the R1 code shape (the only one that compiled clean: VGPR 28,
// VALUBusy 72%). Every thread owns its outputs exclusively: 16 accumulators
// s[16] (4 k x 4 l), iterates the FULL i-chunk. No LDS atomics, no cross-wave
// reduce, no role-divergent inner structure — R4-R6's 512-thr/atomic/split
// shapes all compiled to scratch-backed code (VGPR_Count 32-52, VALUBusy 9%,
// ~50 us on L2 scratch round-trips).
#define BLK1  256
#define IC    64                  // i's per block
#define NICH  (N_TOT / IC)        // 128
#define KC    4                   // k's per block
#define NKCH  (N_EMB / KC)        // 4
#define NQ    4                   // l's per thread (l = q*256 + t, covers all 1024)

__global__ __launch_bounds__(BLK1) void gemm_partial_kernel(
    const float* __restrict__ z, const float* __restrict__ emb,
    const float* __restrict__ log_sigma, const float* __restrict__ eps,
    const float* __restrict__ temperature, float* __restrict__ part,
    unsigned int* __restrict__ counter)
{
    __shared__ float4 zt[IC];     // P_ik quad for this block's 4 k's
    __shared__ float2 tb2[IC];    // (T*b0, T*b1) per i

    const int t  = threadIdx.x;
    const int ib = blockIdx.x;    // i-chunk
    const int kb = blockIdx.y;    // k-chunk: k = kb*4 + 0..3

    // zero K2's finalize counter (visible to K2 across the dispatch boundary)
    if (ib == 0 && kb == 0 && t == 0) *counter = 0u;

    const float ls = log_sigma[0];
    const float T  = temperature[0];
    const float alpha = -0.5f * EXP2(LOG2E * (-2.0f * ls));  // -1/(2 sigma^2)
    const float La  = LOG2E * alpha;
    const float omT = 1.0f - T;

    // Stage per-i data: thread t < IC handles i = ib*IC + t (R2-style guard)
    if (t < IC) {
        const int i = ib * IC + t;
        const float z0 = z[2 * i], z1 = z[2 * i + 1];
        const float c  = La * (z0 * z0 + z1 * z1);
        const float b0 = -2.0f * La * z0, b1 = -2.0f * La * z1;
        const int kbase = kb * KC;
#define PCOMP(kk) EXP2(c + b0 * (omT * emb[2 * (kbase + (kk))]) \
                         + b1 * (omT * emb[2 * (kbase + (kk)) + 1]))
        zt[t]  = make_float4(PCOMP(0), PCOMP(1), PCOMP(2), PCOMP(3));
#undef PCOMP
        tb2[t] = make_float2(T * b0, T * b1);
    }

    // This thread's NQ sample offsets u_l, l = q*256 + t (coalesced float2 loads)
    const float2* eps2 = (const float2*)eps;
    float2 u[NQ];
#pragma unroll
    for (int q = 0; q < NQ; ++q) u[q] = eps2[q * BLK1 + t];

    __syncthreads();

    float s[KC * NQ];
#pragma unroll
    for (int r = 0; r < KC * NQ; ++r) s[r] = 0.0f;

    for (int ii = 0; ii < IC; ++ii) {
        const float4 w  = zt[ii];       // wave-uniform broadcast (b128)
        const float2 tb = tb2[ii];      // broadcast (b64)
        float qv[NQ];
#pragma unroll
        for (int q = 0; q < NQ; ++q)
            qv[q] = EXP2(fmaf(tb.y, u[q].y, tb.x * u[q].x));   // Q_il
#pragma unroll
        for (int q = 0; q < NQ; ++q) {
            s[0 * NQ + q] = fmaf(w.x, qv[q], s[0 * NQ + q]);
            s[1 * NQ + q] = fmaf(w.y, qv[q], s[1 * NQ + q]);
            s[2 * NQ + q] = fmaf(w.z, qv[q], s[2 * NQ + q]);
            s[3 * NQ + q] = fmaf(w.w, qv[q], s[3 * NQ + q]);
        }
    }

    // Each thread exclusively owns its 16 outputs: part[ib][k][l], coalesced per (k,q)
#pragma unroll
    for (int kt = 0; kt < KC; ++kt)
#pragma unroll
        for (int q = 0; q < NQ; ++q)
            part[(size_t)ib * M_TOT + (kb * KC + kt) * EPS_N + q * BLK1 + t] = s[kt * NQ + q];
}

// K2: combine partials, v_j = g_j + log2(S_j); block scalar; last block finalizes loss
#define BLK2 256
__global__ __launch_bounds__(BLK2) void reduce_final_kernel(
    const float* __restrict__ emb, const float* __restrict__ log_sigma,
    const float* __restrict__ eps, const float* __restrict__ temperature,
    const float* __restrict__ part, float* __restrict__ sc,
    unsigned int* __restrict__ counter, float* __restrict__ out)
{
    const int t = threadIdx.x;
    const int j = blockIdx.x * BLK2 + t;
    const float ls = log_sigma[0];
    const float T  = temperature[0];
    const float alpha = -0.5f * EXP2(LOG2E * (-2.0f * ls));

    float S = 0.0f;
#pragma unroll 8
    for (int ib = 0; ib < NICH; ++ib)
        S += part[(size_t)ib * M_TOT + j];      // coalesced across threads

    const int k = j >> 10, l = j & (EPS_N - 1);
    const float omT = 1.0f - T;
    const float e0 = omT * emb[2 * k]     + T * eps[2 * l];
    const float e1 = omT * emb[2 * k + 1] + T * eps[2 * l + 1];
    const float g  = LOG2E * alpha * (e0 * e0 + e1 * e1);   // factored-out 2^g

    float v = g + LOG2F_(S);                    // lse_j / ln2

#pragma unroll
    for (int off = 32; off; off >>= 1) v += __shfl_down(v, off, 64);
    __shared__ float wsum[BLK2 / 64];
    const int lane = t & 63, w = t >> 6;
    if (lane == 0) wsum[w] = v;
    __syncthreads();

    __shared__ int is_last;
    if (t == 0) {
        sc[blockIdx.x] = wsum[0] + wsum[1] + wsum[2] + wsum[3];
        __threadfence();                        // release block scalar
        unsigned int old = atomicAdd(counter, 1u);
        is_last = (old == (unsigned)(M_TOT / BLK2 - 1));
    }
    __syncthreads();

    if (is_last && t < 64) {
        __threadfence();                        // acquire other blocks' scalars
        float x = sc[t];                        // exactly 64 block scalars
#pragma unroll
        for (int off = 32; off; off >>= 1) x += __shfl_down(x, off, 64);
        if (t == 0) {
            const float sum_lse = x * LN2;
            // loss = -mean(lse) + 0.5*z_dim*(2*ls - 1) + log(n);  z_dim=2, n=8192
            out[0] = -sum_lse / (float)M_TOT + (2.0f * ls - 1.0f) + 9.010913347279288f;
        }
    }
}

extern "C" void kernel_launch(void* const* d_in, const int* in_sizes, int n_in,
                              void* d_out, int out_size, void* d_ws, size_t ws_size,
                              hipStream_t stream)
{
    const float* z    = (const float*)d_in[0];
    const float* emb  = (const float*)d_in[1];
    const float* lsig = (const float*)d_in[2];
    const float* eps  = (const float*)d_in[3];
    const float* temp = (const float*)d_in[4];

    float*        part    = (float*)d_ws;                    // 128 x 16384 floats = 8 MB
    float*        sc      = part + (size_t)NICH * M_TOT;     // 64 floats
    unsigned int* counter = (unsigned int*)(sc + 64);        // 1 uint (zeroed by K1)

    dim3 grid1(NICH, NKCH);                                  // 128 x 4 = 512 blocks
    gemm_partial_kernel<<<grid1, BLK1, 0, stream>>>(z, emb, lsig, eps, temp, part, counter);
    reduce_final_kernel<<<M_TOT / BLK2, BLK2, 0, stream>>>(emb, lsig, eps, temp, part, sc,
                                                           counter, (float*)d_out);
}

// Round 8
// 78.127 us; speedup vs baseline: 1.4753x; 1.0442x over previous
//
#include <hip/hip_runtime.h>
#include <math.h>

// Problem constants (fixed by reference setup_inputs)
#define N_TOT 8192
#define M_TOT 16384
#define EPS_N 1024
#define N_EMB 16

#define LOG2E 1.4426950408889634f
#define LN2   0.6931471805599453f
#define EXP2(x)   __builtin_amdgcn_exp2f(x)   // v_exp_f32
#define LOG2F_(x) __builtin_amdgcn_logf(x)    // v_log_f32 (log2)

// K1: product-grid factorization e_j = m_k + T*u_l  (j = k*1024 + l)
//   t_ij = A_ik + B_il,  P=2^A, Q=2^B, S_kl = sum_i P_ik Q_il
//
// R8: R7's proven-clean code shape (256 thr, t<IC staging guard, per-thread-
// exclusive outputs, constant-indexed unrolled arrays — VGPR ~28, no scratch),
// with IC=128 so NICH=64: partial round-trip halves (16->8 MB), K2 ib-loop
// halves. l split across grid.z (LSPL=2) keeps 512 blocks = 2 waves/SIMD.
// DO NOT reintroduce: 512-thr blocks, LDS atomics, float4 punning of privates
// (R4-R6: all compiled to scratch-backed code, ~50 us, VALUBusy 9%).
#define BLK1  256
#define IC    128                 // i's per block
#define NICH  (N_TOT / IC)        // 64
#define KC    4                   // k's per block
#define NKCH  (N_EMB / KC)        // 4
#define NQ    2                   // l's per thread
#define LCH   (BLK1 * NQ)         // 512 l's per block
#define LSPL  (EPS_N / LCH)       // 2 l-chunks

__global__ __launch_bounds__(BLK1) void gemm_partial_kernel(
    const float* __restrict__ z, const float* __restrict__ emb,
    const float* __restrict__ log_sigma, const float* __restrict__ eps,
    const float* __restrict__ temperature, float* __restrict__ part,
    unsigned int* __restrict__ counter)
{
    __shared__ float4 zt[IC];     // P_ik quad for this block's 4 k's
    __shared__ float2 tb2[IC];    // (T*b0, T*b1) per i

    const int t  = threadIdx.x;
    const int ib = blockIdx.x;    // i-chunk
    const int kb = blockIdx.y;    // k-chunk: k = kb*4 + 0..3
    const int lz = blockIdx.z;    // l-half: l = lz*512 + q*256 + t

    // zero K2's finalize counter (visible to K2 across the dispatch boundary)
    if (ib == 0 && kb == 0 && lz == 0 && t == 0) *counter = 0u;

    const float ls = log_sigma[0];
    const float T  = temperature[0];
    const float alpha = -0.5f * EXP2(LOG2E * (-2.0f * ls));  // -1/(2 sigma^2)
    const float La  = LOG2E * alpha;
    const float omT = 1.0f - T;

    // Stage per-i data: threads 0..127 handle i = ib*IC + t (R2-style guard)
    if (t < IC) {
        const int i = ib * IC + t;
        const float z0 = z[2 * i], z1 = z[2 * i + 1];
        const float c  = La * (z0 * z0 + z1 * z1);
        const float b0 = -2.0f * La * z0, b1 = -2.0f * La * z1;
        const int kbase = kb * KC;
#define PCOMP(kk) EXP2(c + b0 * (omT * emb[2 * (kbase + (kk))]) \
                         + b1 * (omT * emb[2 * (kbase + (kk)) + 1]))
        zt[t]  = make_float4(PCOMP(0), PCOMP(1), PCOMP(2), PCOMP(3));
#undef PCOMP
        tb2[t] = make_float2(T * b0, T * b1);
    }

    // This thread's NQ sample offsets u_l (coalesced float2 loads)
    const float2* eps2 = (const float2*)eps;
    float2 u[NQ];
#pragma unroll
    for (int q = 0; q < NQ; ++q) u[q] = eps2[lz * LCH + q * BLK1 + t];

    __syncthreads();

    float s[KC * NQ];
#pragma unroll
    for (int r = 0; r < KC * NQ; ++r) s[r] = 0.0f;

#pragma unroll 2
    for (int ii = 0; ii < IC; ++ii) {
        const float4 w  = zt[ii];       // wave-uniform broadcast (b128)
        const float2 tb = tb2[ii];      // broadcast (b64)
        float qv[NQ];
#pragma unroll
        for (int q = 0; q < NQ; ++q)
            qv[q] = EXP2(fmaf(tb.y, u[q].y, tb.x * u[q].x));   // Q_il
#pragma unroll
        for (int q = 0; q < NQ; ++q) {
            s[0 * NQ + q] = fmaf(w.x, qv[q], s[0 * NQ + q]);
            s[1 * NQ + q] = fmaf(w.y, qv[q], s[1 * NQ + q]);
            s[2 * NQ + q] = fmaf(w.z, qv[q], s[2 * NQ + q]);
            s[3 * NQ + q] = fmaf(w.w, qv[q], s[3 * NQ + q]);
        }
    }

    // Each thread exclusively owns its 8 outputs: part[ib][k][l], coalesced per (k,q)
#pragma unroll
    for (int kt = 0; kt < KC; ++kt)
#pragma unroll
        for (int q = 0; q < NQ; ++q)
            part[(size_t)ib * M_TOT + (kb * KC + kt) * EPS_N + lz * LCH + q * BLK1 + t]
                = s[kt * NQ + q];
}

// K2: combine partials, v_j = g_j + log2(S_j); block scalar; last block finalizes loss
#define BLK2 256
__global__ __launch_bounds__(BLK2) void reduce_final_kernel(
    const float* __restrict__ emb, const float* __restrict__ log_sigma,
    const float* __restrict__ eps, const float* __restrict__ temperature,
    const float* __restrict__ part, float* __restrict__ sc,
    unsigned int* __restrict__ counter, float* __restrict__ out)
{
    const int t = threadIdx.x;
    const int j = blockIdx.x * BLK2 + t;
    const float ls = log_sigma[0];
    const float T  = temperature[0];
    const float alpha = -0.5f * EXP2(LOG2E * (-2.0f * ls));

    float S = 0.0f;
#pragma unroll 8
    for (int ib = 0; ib < NICH; ++ib)
        S += part[(size_t)ib * M_TOT + j];      // coalesced across threads

    const int k = j >> 10, l = j & (EPS_N - 1);
    const float omT = 1.0f - T;
    const float e0 = omT * emb[2 * k]     + T * eps[2 * l];
    const float e1 = omT * emb[2 * k + 1] + T * eps[2 * l + 1];
    const float g  = LOG2E * alpha * (e0 * e0 + e1 * e1);   // factored-out 2^g

    float v = g + LOG2F_(S);                    // lse_j / ln2

#pragma unroll
    for (int off = 32; off; off >>= 1) v += __shfl_down(v, off, 64);
    __shared__ float wsum[BLK2 / 64];
    const int lane = t & 63, w = t >> 6;
    if (lane == 0) wsum[w] = v;
    __syncthreads();

    __shared__ int is_last;
    if (t == 0) {
        sc[blockIdx.x] = wsum[0] + wsum[1] + wsum[2] + wsum[3];
        __threadfence();                        // release block scalar
        unsigned int old = atomicAdd(counter, 1u);
        is_last = (old == (unsigned)(M_TOT / BLK2 - 1));
    }
    __syncthreads();

    if (is_last && t < 64) {
        __threadfence();                        // acquire other blocks' scalars
        float x = sc[t];                        // exactly 64 block scalars
#pragma unroll
        for (int off = 32; off; off >>= 1) x += __shfl_down(x, off, 64);
        if (t == 0) {
            const float sum_lse = x * LN2;
            // loss = -mean(lse) + 0.5*z_dim*(2*ls - 1) + log(n);  z_dim=2, n=8192
            out[0] = -sum_lse / (float)M_TOT + (2.0f * ls - 1.0f) + 9.010913347279288f;
        }
    }
}

extern "C" void kernel_launch(void* const* d_in, const int* in_sizes, int n_in,
                              void* d_out, int out_size, void* d_ws, size_t ws_size,
                              hipStream_t stream)
{
    const float* z    = (const float*)d_in[0];
    const float* emb  = (const float*)d_in[1];
    const float* lsig = (const float*)d_in[2];
    const float* eps  = (const float*)d_in[3];
    const float* temp = (const float*)d_in[4];

    float*        part    = (float*)d_ws;                    // 64 x 16384 floats = 4 MB
    float*        sc      = part + (size_t)NICH * M_TOT;     // 64 floats
    unsigned int* counter = (unsigned int*)(sc + 64);        // 1 uint (zeroed by K1)

    dim3 grid1(NICH, NKCH, LSPL);                            // 64 x 4 x 2 = 512 blocks
    gemm_partial_kernel<<<grid1, BLK1, 0, stream>>>(z, emb, lsig, eps, temp, part, counter);
    reduce_final_kernel<<<M_TOT / BLK2, BLK2, 0, stream>>>(emb, lsig, eps, temp, part, sc,
                                                           counter, (float*)d_out);
}